// Round 2
// baseline (2409.066 us; speedup 1.0000x reference)
//
#include <hip/hip_runtime.h>

// DeltaNet chunkwise delta-rule, fp32 end-to-end.
// Phase 1: per-chunk factorization (parallel over 4096 chunks).
// Phase 2: sequential chunk scan, parallel over 16 (b,h) x 16 dv-groups.
// Round 1 resubmit: round-0 bench never ran (GPU broker timeout, then
// container failure x2). Kernel re-audited for correctness; unchanged.

static constexpr int BH   = 16;      // b*h
static constexpr int LQ   = 8192;    // sequence length
static constexpr int DK   = 128;     // head dim (dk == dv)
static constexpr int CC   = 32;      // chunk size
static constexpr int NCH  = LQ / CC; // 256 chunks
static constexpr int LDP  = 132;     // padded stride for [32][128] fp32 LDS tiles
static constexpr int TP   = 36;      // padded stride for 32x32 tiles

// workspace layout (in floats)
static constexpr size_t W_OFF  = 0;
static constexpr size_t U0_OFF = (size_t)BH * NCH * CC * DK;            // 16777216
static constexpr size_t AT_OFF = U0_OFF * 2;                             // 33554432
static constexpr size_t RQ_OFF = AT_OFF + (size_t)BH * NCH * CC * CC;    // 37748736
static constexpr size_t RK_OFF = RQ_OFF + (size_t)BH * LQ;               // 37879808
// total floats = RK_OFF + BH*LQ = 38010880  (~152 MiB)

__global__ __launch_bounds__(256) void dn_phase1(
    const float* __restrict__ q, const float* __restrict__ k,
    const float* __restrict__ v, const float* __restrict__ beta,
    float* __restrict__ ws)
{
    __shared__ float qc[CC][LDP];
    __shared__ float kc[CC][LDP];
    __shared__ float vc[CC][LDP];
    __shared__ float T[CC][TP];
    __shared__ float betas[CC], rqs[CC], rks[CC];

    const int tid = threadIdx.x;
    const int blk = blockIdx.x;
    const int bh  = blk >> 8;    // / NCH
    const int t   = blk & 255;   // % NCH
    const size_t gbase = ((size_t)bh * LQ + (size_t)t * CC) * DK;

    // ---- stage q,k,v chunks (4096 floats each), coalesced float4 ----
    #pragma unroll
    for (int i = 0; i < 4; ++i) {
        int idx4 = i * 256 + tid;          // 0..1023
        int row  = idx4 >> 5;
        int c4   = (idx4 & 31) << 2;
        *(float4*)&qc[row][c4] = *(const float4*)(q + gbase + (size_t)idx4 * 4);
        *(float4*)&kc[row][c4] = *(const float4*)(k + gbase + (size_t)idx4 * 4);
        *(float4*)&vc[row][c4] = *(const float4*)(v + gbase + (size_t)idx4 * 4);
    }
    if (tid < CC) betas[tid] = beta[(size_t)bh * LQ + (size_t)t * CC + tid];
    __syncthreads();

    // ---- row l2-norm factors: 8 threads per row ----
    {
        int row = tid >> 3, g = tid & 7;
        float sq = 0.f, sk = 0.f;
        #pragma unroll
        for (int i = 0; i < 4; ++i) {
            float4 a = *(float4*)&qc[row][g * 16 + i * 4];
            sq += a.x * a.x + a.y * a.y + a.z * a.z + a.w * a.w;
            float4 b = *(float4*)&kc[row][g * 16 + i * 4];
            sk += b.x * b.x + b.y * b.y + b.z * b.z + b.w * b.w;
        }
        sq += __shfl_xor(sq, 1); sq += __shfl_xor(sq, 2); sq += __shfl_xor(sq, 4);
        sk += __shfl_xor(sk, 1); sk += __shfl_xor(sk, 2); sk += __shfl_xor(sk, 4);
        if (g == 0) {
            rqs[row] = 1.f / sqrtf(sq + 1e-6f);
            rks[row] = 1.f / sqrtf(sk + 1e-6f);
        }
    }
    __syncthreads();

    // persist norm factors for phase 2
    if (tid < CC) {
        ws[RQ_OFF + (size_t)bh * LQ + (size_t)t * CC + tid] = rqs[tid];
        ws[RK_OFF + (size_t)bh * LQ + (size_t)t * CC + tid] = rks[tid];
    }

    // ---- normalize qc,kc in place (vc stays raw; beta folded later) ----
    #pragma unroll
    for (int i = 0; i < 4; ++i) {
        int idx4 = i * 256 + tid;
        int row  = idx4 >> 5;
        int c4   = (idx4 & 31) << 2;
        float rq_ = rqs[row], rk_ = rks[row];
        float4 a = *(float4*)&qc[row][c4];
        a.x *= rq_; a.y *= rq_; a.z *= rq_; a.w *= rq_;
        *(float4*)&qc[row][c4] = a;
        float4 b = *(float4*)&kc[row][c4];
        b.x *= rk_; b.y *= rk_; b.z *= rk_; b.w *= rk_;
        *(float4*)&kc[row][c4] = b;
    }
    __syncthreads();

    // ---- A (into T, strictly lower) and attn (lower incl. diag), fused dots ----
    {
        int i  = tid >> 3;
        int j0 = (tid & 7) << 2;
        float aA[4] = {0.f, 0.f, 0.f, 0.f};
        float aQ[4] = {0.f, 0.f, 0.f, 0.f};
        for (int r4 = 0; r4 < 32; ++r4) {
            float4 ki = *(float4*)&kc[i][r4 << 2];
            float4 qi = *(float4*)&qc[i][r4 << 2];
            #pragma unroll
            for (int jj = 0; jj < 4; ++jj) {
                float4 kj = *(float4*)&kc[j0 + jj][r4 << 2];
                aA[jj] += ki.x * kj.x + ki.y * kj.y + ki.z * kj.z + ki.w * kj.w;
                aQ[jj] += qi.x * kj.x + qi.y * kj.y + qi.z * kj.z + qi.w * kj.w;
            }
        }
        float bi = betas[i];
        float at4[4];
        #pragma unroll
        for (int jj = 0; jj < 4; ++jj) {
            int j = j0 + jj;
            T[i][j] = (j < i) ? (-bi * aA[jj]) : 0.f;
            at4[jj] = (j <= i) ? aQ[jj] : 0.f;
        }
        *(float4*)(ws + AT_OFF + ((size_t)(bh * NCH + t) * CC + i) * CC + j0) =
            make_float4(at4[0], at4[1], at4[2], at4[3]);
    }
    __syncthreads();

    // ---- forward substitution: T <- strict-lower of (I - A)^-1 ----
    for (int i = 1; i < CC; ++i) {
        float upd = 0.f;
        if (tid < i) {
            float s = T[i][tid];
            for (int j = 0; j < CC; ++j) s += T[i][j] * T[j][tid];
            upd = s;
        }
        __syncthreads();
        if (tid < i) T[i][tid] = upd;
        __syncthreads();
    }

    // ---- fold beta into T columns: Tb[i][j] = T[i][j] * beta[j] ----
    {
        int i  = tid >> 3;
        int j0 = (tid & 7) << 2;
        #pragma unroll
        for (int jj = 0; jj < 4; ++jj) T[i][j0 + jj] *= betas[j0 + jj];
    }
    __syncthreads();

    // ---- u0 = (T+I) @ (beta*v), w = (T+I) @ (beta*kn) ----
    {
        int i  = tid >> 3;
        int d0 = (tid & 7) << 4;     // 16 d-values per thread
        float bi = betas[i];
        float4 aU[4], aW[4];
        #pragma unroll
        for (int d4 = 0; d4 < 4; ++d4) {
            float4 vv = *(float4*)&vc[i][d0 + d4 * 4];
            float4 kk = *(float4*)&kc[i][d0 + d4 * 4];
            aU[d4] = make_float4(bi * vv.x, bi * vv.y, bi * vv.z, bi * vv.w);
            aW[d4] = make_float4(bi * kk.x, bi * kk.y, bi * kk.z, bi * kk.w);
        }
        for (int j = 0; j < i; ++j) {     // Tb strictly lower
            float tb = T[i][j];
            #pragma unroll
            for (int d4 = 0; d4 < 4; ++d4) {
                float4 vv = *(float4*)&vc[j][d0 + d4 * 4];
                float4 kk = *(float4*)&kc[j][d0 + d4 * 4];
                aU[d4].x += tb * vv.x; aU[d4].y += tb * vv.y;
                aU[d4].z += tb * vv.z; aU[d4].w += tb * vv.w;
                aW[d4].x += tb * kk.x; aW[d4].y += tb * kk.y;
                aW[d4].z += tb * kk.z; aW[d4].w += tb * kk.w;
            }
        }
        size_t ob = (size_t)(bh * NCH + t) * (CC * DK) + (size_t)i * DK + d0;
        #pragma unroll
        for (int d4 = 0; d4 < 4; ++d4) {
            *(float4*)(ws + U0_OFF + ob + d4 * 4) = aU[d4];
            *(float4*)(ws + W_OFF  + ob + d4 * 4) = aW[d4];
        }
    }
}

__global__ __launch_bounds__(64) void dn_phase2(
    const float* __restrict__ q, const float* __restrict__ k,
    const float* __restrict__ ws, float* __restrict__ out)
{
    __shared__ float wl[CC][LDP];
    __shared__ float kl[CC][LDP];
    __shared__ float ql[CC][LDP];
    __shared__ float at[CC][TP];
    __shared__ float St[8][LDP];     // S transposed: St[col][r], r<128
    __shared__ float um[CC][12];     // u rows
    __shared__ float u2m[CC][12];    // rk * u rows
    __shared__ float u0s[CC][8];
    __shared__ float rqs[CC], rks[CC];

    const int bh = blockIdx.x >> 4;
    const int g  = blockIdx.x & 15;
    const int c0 = g * 8;            // dv column slice [c0, c0+8)
    const int l  = threadIdx.x;      // 0..63
    const int a  = l & 31;
    const int cp = l >> 5;           // col sub-group: cols 4*cp..4*cp+3 (local)

    // zero S
    for (int idx = l; idx < 8 * LDP; idx += 64) ((float*)St)[idx] = 0.f;
    __syncthreads();

    for (int t = 0; t < NCH; ++t) {
        const size_t wbase  = (size_t)(bh * NCH + t) * (CC * DK);
        const size_t qkbase = ((size_t)bh * LQ + (size_t)t * CC) * DK;
        const size_t atbase = AT_OFF + (size_t)(bh * NCH + t) * (CC * CC);

        // ---- stage chunk operands ----
        #pragma unroll 4
        for (int i = 0; i < 16; ++i) {
            int idx4 = i * 64 + l;             // 0..1023
            int row  = idx4 >> 5;
            int c4   = (idx4 & 31) << 2;
            *(float4*)&wl[row][c4] = *(const float4*)(ws + W_OFF + wbase + (size_t)idx4 * 4);
            *(float4*)&kl[row][c4] = *(const float4*)(k + qkbase + (size_t)idx4 * 4);
            *(float4*)&ql[row][c4] = *(const float4*)(q + qkbase + (size_t)idx4 * 4);
        }
        #pragma unroll
        for (int i = 0; i < 4; ++i) {
            int idx4 = i * 64 + l;             // 0..255
            int row  = idx4 >> 3;
            int j4   = (idx4 & 7) << 2;
            *(float4*)&at[row][j4] = *(const float4*)(ws + atbase + (size_t)idx4 * 4);
        }
        {
            int row = l >> 1, cc4 = (l & 1) << 2;
            *(float4*)&u0s[row][cc4] =
                *(const float4*)(ws + U0_OFF + wbase + (size_t)row * DK + c0 + cc4);
        }
        if (l < CC)  rqs[l]      = ws[RQ_OFF + (size_t)bh * LQ + (size_t)t * CC + l];
        else         rks[l - 32] = ws[RK_OFF + (size_t)bh * LQ + (size_t)t * CC + (l - 32)];
        __syncthreads();

        // ---- fused: u = u0 - w@S  and  qdot = q@S  (K = 128) ----
        float au[4], aq[4];
        #pragma unroll
        for (int cc = 0; cc < 4; ++cc) { au[cc] = u0s[a][(cp << 2) + cc]; aq[cc] = 0.f; }
        #pragma unroll 4
        for (int r4 = 0; r4 < 32; ++r4) {
            float4 wv = *(float4*)&wl[a][r4 << 2];
            float4 qv = *(float4*)&ql[a][r4 << 2];
            #pragma unroll
            for (int cc = 0; cc < 4; ++cc) {
                float4 sv = *(float4*)&St[(cp << 2) + cc][r4 << 2];
                au[cc] -= wv.x * sv.x + wv.y * sv.y + wv.z * sv.z + wv.w * sv.w;
                aq[cc] += qv.x * sv.x + qv.y * sv.y + qv.z * sv.z + qv.w * sv.w;
            }
        }
        // publish u and rk*u
        {
            float rk_ = rks[a];
            *(float4*)&um[a][cp << 2]  = make_float4(au[0], au[1], au[2], au[3]);
            *(float4*)&u2m[a][cp << 2] =
                make_float4(au[0] * rk_, au[1] * rk_, au[2] * rk_, au[3] * rk_);
        }
        float ao[4];
        {
            float rq_ = rqs[a];
            #pragma unroll
            for (int cc = 0; cc < 4; ++cc) ao[cc] = rq_ * aq[cc];
        }
        __syncthreads();   // um/u2m visible; everyone done reading St

        // ---- o += attn @ u  (attn stored pre-masked lower-incl) ----
        #pragma unroll 2
        for (int j4 = 0; j4 < 8; ++j4) {
            float4 av = *(float4*)&at[a][j4 << 2];
            float aw[4] = {av.x, av.y, av.z, av.w};
            #pragma unroll
            for (int jj = 0; jj < 4; ++jj) {
                float4 uv = *(float4*)&um[(j4 << 2) + jj][cp << 2];
                ao[0] += aw[jj] * uv.x; ao[1] += aw[jj] * uv.y;
                ao[2] += aw[jj] * uv.z; ao[3] += aw[jj] * uv.w;
            }
        }
        *(float4*)(out + ((size_t)bh * LQ + (size_t)t * CC + a) * DK + c0 + (cp << 2)) =
            make_float4(ao[0], ao[1], ao[2], ao[3]);

        // ---- S += kn^T @ u : thread l owns rows {l, l+64}, all 8 cols ----
        {
            float s0[8] = {0,0,0,0,0,0,0,0}, s1[8] = {0,0,0,0,0,0,0,0};
            #pragma unroll 4
            for (int j = 0; j < CC; ++j) {
                float k0 = kl[j][l];
                float k1 = kl[j][l + 64];
                float4 ua = *(float4*)&u2m[j][0];
                float4 ub = *(float4*)&u2m[j][4];
                s0[0] += k0 * ua.x; s0[1] += k0 * ua.y; s0[2] += k0 * ua.z; s0[3] += k0 * ua.w;
                s0[4] += k0 * ub.x; s0[5] += k0 * ub.y; s0[6] += k0 * ub.z; s0[7] += k0 * ub.w;
                s1[0] += k1 * ua.x; s1[1] += k1 * ua.y; s1[2] += k1 * ua.z; s1[3] += k1 * ua.w;
                s1[4] += k1 * ub.x; s1[5] += k1 * ub.y; s1[6] += k1 * ub.z; s1[7] += k1 * ub.w;
            }
            #pragma unroll
            for (int col = 0; col < 8; ++col) {
                St[col][l]      += s0[col];
                St[col][l + 64] += s1[col];
            }
        }
        __syncthreads();   // St updated; safe to restage next chunk
    }

    // ---- final state S -> out (after o block) ----
    const size_t sbase = (size_t)BH * LQ * DK + (size_t)bh * DK * DK;
    #pragma unroll
    for (int col = 0; col < 8; ++col) {
        out[sbase + (size_t)l * DK + c0 + col]        = St[col][l];
        out[sbase + (size_t)(l + 64) * DK + c0 + col] = St[col][l + 64];
    }
}

extern "C" void kernel_launch(void* const* d_in, const int* in_sizes, int n_in,
                              void* d_out, int out_size, void* d_ws, size_t ws_size,
                              hipStream_t stream) {
    (void)in_sizes; (void)n_in; (void)out_size; (void)ws_size;
    const float* q    = (const float*)d_in[0];
    const float* k    = (const float*)d_in[1];
    const float* v    = (const float*)d_in[2];
    const float* beta = (const float*)d_in[3];
    float* ws  = (float*)d_ws;
    float* out = (float*)d_out;

    dn_phase1<<<BH * NCH, 256, 0, stream>>>(q, k, v, beta, ws);
    dn_phase2<<<BH * 16, 64, 0, stream>>>(q, k, ws, out);
}

// Round 3
// 1199.947 us; speedup vs baseline: 2.0076x; 2.0076x over previous
//
#include <hip/hip_runtime.h>

// DeltaNet chunkwise delta-rule, fp32 end-to-end.
// Phase 1 (unchanged from round 2): per-chunk factorization, 4096 blocks.
// Phase 2 (rewritten): sequential chunk scan; 256 blocks (16 bh x 16 dv-groups),
//   256 threads (4 waves = 1 wave/SIMD). S[128x8] lives in registers of
//   (k,colpair) owner threads, published to padded LDS St[8][132] each step.
//   Double-buffered reg-staging (T14): issue t+1 global loads at step top,
//   ds_write commit at step end. All LDS tiles padded (stride 132 / 36):
//   b128 quad-slot = (row+col)%8 -> conflict-free. 2 barriers/step.

static constexpr int BH   = 16;      // b*h
static constexpr int LQ   = 8192;    // sequence length
static constexpr int DK   = 128;     // head dim (dk == dv)
static constexpr int CC   = 32;      // chunk size
static constexpr int NCH  = LQ / CC; // 256 chunks
static constexpr int LDP  = 132;     // padded stride for [32][128] fp32 LDS tiles
static constexpr int TP   = 36;      // padded stride for 32x32 tiles

// workspace layout (in floats)
static constexpr size_t W_OFF  = 0;
static constexpr size_t U0_OFF = (size_t)BH * NCH * CC * DK;            // 16777216
static constexpr size_t AT_OFF = U0_OFF * 2;                             // 33554432
static constexpr size_t RQ_OFF = AT_OFF + (size_t)BH * NCH * CC * CC;    // 37748736
static constexpr size_t RK_OFF = RQ_OFF + (size_t)BH * LQ;               // 37879808
// total floats = RK_OFF + BH*LQ = 38010880  (~152 MiB)

__global__ __launch_bounds__(256) void dn_phase1(
    const float* __restrict__ q, const float* __restrict__ k,
    const float* __restrict__ v, const float* __restrict__ beta,
    float* __restrict__ ws)
{
    __shared__ float qc[CC][LDP];
    __shared__ float kc[CC][LDP];
    __shared__ float vc[CC][LDP];
    __shared__ float T[CC][TP];
    __shared__ float betas[CC], rqs[CC], rks[CC];

    const int tid = threadIdx.x;
    const int blk = blockIdx.x;
    const int bh  = blk >> 8;    // / NCH
    const int t   = blk & 255;   // % NCH
    const size_t gbase = ((size_t)bh * LQ + (size_t)t * CC) * DK;

    // ---- stage q,k,v chunks (4096 floats each), coalesced float4 ----
    #pragma unroll
    for (int i = 0; i < 4; ++i) {
        int idx4 = i * 256 + tid;          // 0..1023
        int row  = idx4 >> 5;
        int c4   = (idx4 & 31) << 2;
        *(float4*)&qc[row][c4] = *(const float4*)(q + gbase + (size_t)idx4 * 4);
        *(float4*)&kc[row][c4] = *(const float4*)(k + gbase + (size_t)idx4 * 4);
        *(float4*)&vc[row][c4] = *(const float4*)(v + gbase + (size_t)idx4 * 4);
    }
    if (tid < CC) betas[tid] = beta[(size_t)bh * LQ + (size_t)t * CC + tid];
    __syncthreads();

    // ---- row l2-norm factors: 8 threads per row ----
    {
        int row = tid >> 3, g = tid & 7;
        float sq = 0.f, sk = 0.f;
        #pragma unroll
        for (int i = 0; i < 4; ++i) {
            float4 a = *(float4*)&qc[row][g * 16 + i * 4];
            sq += a.x * a.x + a.y * a.y + a.z * a.z + a.w * a.w;
            float4 b = *(float4*)&kc[row][g * 16 + i * 4];
            sk += b.x * b.x + b.y * b.y + b.z * b.z + b.w * b.w;
        }
        sq += __shfl_xor(sq, 1); sq += __shfl_xor(sq, 2); sq += __shfl_xor(sq, 4);
        sk += __shfl_xor(sk, 1); sk += __shfl_xor(sk, 2); sk += __shfl_xor(sk, 4);
        if (g == 0) {
            rqs[row] = 1.f / sqrtf(sq + 1e-6f);
            rks[row] = 1.f / sqrtf(sk + 1e-6f);
        }
    }
    __syncthreads();

    // persist norm factors for phase 2
    if (tid < CC) {
        ws[RQ_OFF + (size_t)bh * LQ + (size_t)t * CC + tid] = rqs[tid];
        ws[RK_OFF + (size_t)bh * LQ + (size_t)t * CC + tid] = rks[tid];
    }

    // ---- normalize qc,kc in place (vc stays raw; beta folded later) ----
    #pragma unroll
    for (int i = 0; i < 4; ++i) {
        int idx4 = i * 256 + tid;
        int row  = idx4 >> 5;
        int c4   = (idx4 & 31) << 2;
        float rq_ = rqs[row], rk_ = rks[row];
        float4 a = *(float4*)&qc[row][c4];
        a.x *= rq_; a.y *= rq_; a.z *= rq_; a.w *= rq_;
        *(float4*)&qc[row][c4] = a;
        float4 b = *(float4*)&kc[row][c4];
        b.x *= rk_; b.y *= rk_; b.z *= rk_; b.w *= rk_;
        *(float4*)&kc[row][c4] = b;
    }
    __syncthreads();

    // ---- A (into T, strictly lower) and attn (lower incl. diag), fused dots ----
    {
        int i  = tid >> 3;
        int j0 = (tid & 7) << 2;
        float aA[4] = {0.f, 0.f, 0.f, 0.f};
        float aQ[4] = {0.f, 0.f, 0.f, 0.f};
        for (int r4 = 0; r4 < 32; ++r4) {
            float4 ki = *(float4*)&kc[i][r4 << 2];
            float4 qi = *(float4*)&qc[i][r4 << 2];
            #pragma unroll
            for (int jj = 0; jj < 4; ++jj) {
                float4 kj = *(float4*)&kc[j0 + jj][r4 << 2];
                aA[jj] += ki.x * kj.x + ki.y * kj.y + ki.z * kj.z + ki.w * kj.w;
                aQ[jj] += qi.x * kj.x + qi.y * kj.y + qi.z * kj.z + qi.w * kj.w;
            }
        }
        float bi = betas[i];
        float at4[4];
        #pragma unroll
        for (int jj = 0; jj < 4; ++jj) {
            int j = j0 + jj;
            T[i][j] = (j < i) ? (-bi * aA[jj]) : 0.f;
            at4[jj] = (j <= i) ? aQ[jj] : 0.f;
        }
        *(float4*)(ws + AT_OFF + ((size_t)(bh * NCH + t) * CC + i) * CC + j0) =
            make_float4(at4[0], at4[1], at4[2], at4[3]);
    }
    __syncthreads();

    // ---- forward substitution: T <- strict-lower of (I - A)^-1 ----
    for (int i = 1; i < CC; ++i) {
        float upd = 0.f;
        if (tid < i) {
            float s = T[i][tid];
            for (int j = 0; j < CC; ++j) s += T[i][j] * T[j][tid];
            upd = s;
        }
        __syncthreads();
        if (tid < i) T[i][tid] = upd;
        __syncthreads();
    }

    // ---- fold beta into T columns: Tb[i][j] = T[i][j] * beta[j] ----
    {
        int i  = tid >> 3;
        int j0 = (tid & 7) << 2;
        #pragma unroll
        for (int jj = 0; jj < 4; ++jj) T[i][j0 + jj] *= betas[j0 + jj];
    }
    __syncthreads();

    // ---- u0 = (T+I) @ (beta*v), w = (T+I) @ (beta*kn) ----
    {
        int i  = tid >> 3;
        int d0 = (tid & 7) << 4;     // 16 d-values per thread
        float bi = betas[i];
        float4 aU[4], aW[4];
        #pragma unroll
        for (int d4 = 0; d4 < 4; ++d4) {
            float4 vv = *(float4*)&vc[i][d0 + d4 * 4];
            float4 kk = *(float4*)&kc[i][d0 + d4 * 4];
            aU[d4] = make_float4(bi * vv.x, bi * vv.y, bi * vv.z, bi * vv.w);
            aW[d4] = make_float4(bi * kk.x, bi * kk.y, bi * kk.z, bi * kk.w);
        }
        for (int j = 0; j < i; ++j) {     // Tb strictly lower
            float tb = T[i][j];
            #pragma unroll
            for (int d4 = 0; d4 < 4; ++d4) {
                float4 vv = *(float4*)&vc[j][d0 + d4 * 4];
                float4 kk = *(float4*)&kc[j][d0 + d4 * 4];
                aU[d4].x += tb * vv.x; aU[d4].y += tb * vv.y;
                aU[d4].z += tb * vv.z; aU[d4].w += tb * vv.w;
                aW[d4].x += tb * kk.x; aW[d4].y += tb * kk.y;
                aW[d4].z += tb * kk.z; aW[d4].w += tb * kk.w;
            }
        }
        size_t ob = (size_t)(bh * NCH + t) * (CC * DK) + (size_t)i * DK + d0;
        #pragma unroll
        for (int d4 = 0; d4 < 4; ++d4) {
            *(float4*)(ws + U0_OFF + ob + d4 * 4) = aU[d4];
            *(float4*)(ws + W_OFF  + ob + d4 * 4) = aW[d4];
        }
    }
}

// ---------------------------------------------------------------------------
// Phase 2 v2: 256 threads/block, 4 waves, dv-slice of 8 columns per block.
// Thread roles:
//   (a = tid>>3 in 0..31, c = tid&7)  : u/q reduction + attn + o store
//   (k2 = tid&127, ch = tid>>7)       : S-update owner of S[k2][c0+4ch..+3]
// ---------------------------------------------------------------------------
__global__ __launch_bounds__(256) void dn_phase2(
    const float* __restrict__ q, const float* __restrict__ k,
    const float* __restrict__ ws, float* __restrict__ out)
{
    __shared__ float wA[CC][LDP], kA[CC][LDP], qA[CC][LDP];
    __shared__ float wB[CC][LDP], kB[CC][LDP], qB[CC][LDP];
    __shared__ float aA_[CC][TP], aB_[CC][TP];
    __shared__ float St[8][LDP];       // S^T slice: St[c][k], padded rows
    __shared__ float um_[CC][12];      // u rows (8 cols used)
    __shared__ float u2_[CC][12];      // rk * u rows

    const int bh  = blockIdx.x >> 4;
    const int g   = blockIdx.x & 15;
    const int c0  = g * 8;             // dv column slice [c0, c0+8)
    const int tid = threadIdx.x;
    const int a   = tid >> 3;          // 0..31 chunk row
    const int c   = tid & 7;           // 0..7 local col
    const int k2  = tid & 127;         // 0..127 S row
    const int ch  = tid >> 7;          // 0..1 col-pair

    float sreg0 = 0.f, sreg1 = 0.f, sreg2 = 0.f, sreg3 = 0.f; // S[k2][c0+4ch+..]

    // zero St
    for (int idx = tid; idx < 8 * LDP; idx += 256) ((float*)St)[idx] = 0.f;

    // staging registers (next chunk)
    float4 sw0, sw1, sw2, sw3, sk0, sk1, sk2_, sk3, sq0, sq1, sq2, sq3, sat;
    float nu0, nrq, nrk;

    auto issue = [&](int t) {
        const size_t wb = W_OFF + (size_t)(bh * NCH + t) * 4096;
        const size_t gb = ((size_t)bh * LQ + (size_t)t * CC) * DK;
        const size_t ab = AT_OFF + (size_t)(bh * NCH + t) * 1024;
        sw0 = *(const float4*)(ws + wb + (size_t)(0 * 256 + tid) * 4);
        sw1 = *(const float4*)(ws + wb + (size_t)(1 * 256 + tid) * 4);
        sw2 = *(const float4*)(ws + wb + (size_t)(2 * 256 + tid) * 4);
        sw3 = *(const float4*)(ws + wb + (size_t)(3 * 256 + tid) * 4);
        sk0 = *(const float4*)(k + gb + (size_t)(0 * 256 + tid) * 4);
        sk1 = *(const float4*)(k + gb + (size_t)(1 * 256 + tid) * 4);
        sk2_ = *(const float4*)(k + gb + (size_t)(2 * 256 + tid) * 4);
        sk3 = *(const float4*)(k + gb + (size_t)(3 * 256 + tid) * 4);
        sq0 = *(const float4*)(q + gb + (size_t)(0 * 256 + tid) * 4);
        sq1 = *(const float4*)(q + gb + (size_t)(1 * 256 + tid) * 4);
        sq2 = *(const float4*)(q + gb + (size_t)(2 * 256 + tid) * 4);
        sq3 = *(const float4*)(q + gb + (size_t)(3 * 256 + tid) * 4);
        sat = *(const float4*)(ws + ab + (size_t)tid * 4);
        nu0 = ws[U0_OFF + (size_t)(bh * NCH + t) * 4096 + (size_t)a * DK + c0 + c];
        nrq = ws[RQ_OFF + (size_t)bh * LQ + (size_t)t * CC + a];
        nrk = ws[RK_OFF + (size_t)bh * LQ + (size_t)t * CC + a];
    };

    auto commit = [&](float (*wT)[LDP], float (*kT)[LDP], float (*qT)[LDP],
                      float (*aT)[TP]) {
        // tile float4 index gi = i*256+tid -> row gi>>5, col4 (gi&31)<<2
        {
            int gi = 0 * 256 + tid; int r = gi >> 5, c4 = (gi & 31) << 2;
            *(float4*)&wT[r][c4] = sw0; *(float4*)&kT[r][c4] = sk0; *(float4*)&qT[r][c4] = sq0;
        }
        {
            int gi = 1 * 256 + tid; int r = gi >> 5, c4 = (gi & 31) << 2;
            *(float4*)&wT[r][c4] = sw1; *(float4*)&kT[r][c4] = sk1; *(float4*)&qT[r][c4] = sq1;
        }
        {
            int gi = 2 * 256 + tid; int r = gi >> 5, c4 = (gi & 31) << 2;
            *(float4*)&wT[r][c4] = sw2; *(float4*)&kT[r][c4] = sk2_; *(float4*)&qT[r][c4] = sq2;
        }
        {
            int gi = 3 * 256 + tid; int r = gi >> 5, c4 = (gi & 31) << 2;
            *(float4*)&wT[r][c4] = sw3; *(float4*)&kT[r][c4] = sk3; *(float4*)&qT[r][c4] = sq3;
        }
        { int r = tid >> 3, c4 = (tid & 7) << 2; *(float4*)&aT[r][c4] = sat; }
    };

    float (*wC)[LDP] = wA, (*kC)[LDP] = kA, (*qC)[LDP] = qA;
    float (*wN)[LDP] = wB, (*kN)[LDP] = kB, (*qN)[LDP] = qB;
    float (*aC)[TP] = aA_, (*aN)[TP] = aB_;

    // prologue: stage chunk 0
    issue(0);
    commit(wC, kC, qC, aC);
    float u0r = nu0, rqr = nrq, rkr = nrk;
    __syncthreads();

    for (int t = 0; t < NCH; ++t) {
        // A: issue next chunk's global loads (drained by barrier 1 / commit)
        if (t + 1 < NCH) issue(t + 1);

        // B: u = u0 - w@S ; qdot = q@S  (K=128, b128 conflict-free reads)
        float au = u0r, aq = 0.f;
        #pragma unroll
        for (int j = 0; j < 32; ++j) {
            float4 wv = *(float4*)&wC[a][4 * j];
            float4 qv = *(float4*)&qC[a][4 * j];
            float4 sv = *(float4*)&St[c][4 * j];
            au -= wv.x * sv.x + wv.y * sv.y + wv.z * sv.z + wv.w * sv.w;
            aq += qv.x * sv.x + qv.y * sv.y + qv.z * sv.z + qv.w * sv.w;
        }
        um_[a][c] = au;
        u2_[a][c] = au * rkr;
        float ao = rqr * aq;
        __syncthreads();                       // barrier 1: um/u2 ready

        // C: o = rq*q@S + attn@u, store
        #pragma unroll
        for (int j4 = 0; j4 < 8; ++j4) {
            float4 av = *(float4*)&aC[a][4 * j4];
            ao += av.x * um_[4 * j4 + 0][c] + av.y * um_[4 * j4 + 1][c]
                + av.z * um_[4 * j4 + 2][c] + av.w * um_[4 * j4 + 3][c];
        }
        out[((size_t)bh * LQ + (size_t)t * CC + a) * DK + c0 + c] = ao;

        // D: S += kn^T @ (rk*u): regs, then publish to St
        #pragma unroll
        for (int jj = 0; jj < 32; ++jj) {
            float kv  = kC[jj][k2];
            float4 uv = *(float4*)&u2_[jj][4 * ch];
            sreg0 += kv * uv.x; sreg1 += kv * uv.y;
            sreg2 += kv * uv.z; sreg3 += kv * uv.w;
        }
        St[4 * ch + 0][k2] = sreg0;
        St[4 * ch + 1][k2] = sreg1;
        St[4 * ch + 2][k2] = sreg2;
        St[4 * ch + 3][k2] = sreg3;

        // E: commit staged regs into the other buffer, rotate
        if (t + 1 < NCH) {
            commit(wN, kN, qN, aN);
            u0r = nu0; rqr = nrq; rkr = nrk;
            float (*tp)[LDP];
            tp = wC; wC = wN; wN = tp;
            tp = kC; kC = kN; kN = tp;
            tp = qC; qC = qN; qN = tp;
            float (*ta)[TP] = aC; aC = aN; aN = ta;
        }
        __syncthreads();                       // barrier 2: St + next buffers ready
    }

    // final state S -> out (after o block)
    const size_t sbase = (size_t)BH * LQ * DK + (size_t)bh * DK * DK;
    *(float4*)(out + sbase + (size_t)k2 * DK + c0 + 4 * ch) =
        make_float4(sreg0, sreg1, sreg2, sreg3);
}

extern "C" void kernel_launch(void* const* d_in, const int* in_sizes, int n_in,
                              void* d_out, int out_size, void* d_ws, size_t ws_size,
                              hipStream_t stream) {
    (void)in_sizes; (void)n_in; (void)out_size; (void)ws_size;
    const float* q    = (const float*)d_in[0];
    const float* k    = (const float*)d_in[1];
    const float* v    = (const float*)d_in[2];
    const float* beta = (const float*)d_in[3];
    float* ws  = (float*)d_ws;
    float* out = (float*)d_out;

    dn_phase1<<<BH * NCH, 256, 0, stream>>>(q, k, v, beta, ws);
    dn_phase2<<<BH * 16, 256, 0, stream>>>(q, k, ws, out);
}

// Round 4
// 1188.947 us; speedup vs baseline: 2.0262x; 1.0093x over previous
//
#include <hip/hip_runtime.h>

// DeltaNet chunkwise delta-rule, fp32 end-to-end.
// Phase 1 (unchanged): per-chunk factorization, 4096 blocks x 256 thr.
// Phase 2 v3: sequential chunk scan, 256 blocks (16 bh x 16 dv-groups) x 256 thr.
//   LDS-instruction-bound (r3 counters: step time == LDS pipe cycles), so v3
//   register-tiles every matmul and splits the contraction across lanes with
//   __shfl_xor reduction (no LDS cost):
//     B: [w;q](64x128) @ S(128x8): 4 rows x 4 cols/thread, K/8 on lane bits 0-2
//     C: attn(32x32) @ u(32x8):    2 rows/thread, J/2 on lane bit 0
//     D: k^T(128x32) @ u2(32x8):   2 rows x 4 cols/thread, J/2 on lane bit 5
//   LDS instrs/step: ~1500 -> ~820 wave-instrs (~8600 -> ~4900 cyc predicted).

static constexpr int BH   = 16;      // b*h
static constexpr int LQ   = 8192;    // sequence length
static constexpr int DK   = 128;     // head dim (dk == dv)
static constexpr int CC   = 32;      // chunk size
static constexpr int NCH  = LQ / CC; // 256 chunks
static constexpr int LDP  = 132;     // padded stride for [*][128] fp32 LDS tiles
static constexpr int TP   = 36;      // padded stride for 32x32 tiles

// workspace layout (in floats)
static constexpr size_t W_OFF  = 0;
static constexpr size_t U0_OFF = (size_t)BH * NCH * CC * DK;            // 16777216
static constexpr size_t AT_OFF = U0_OFF * 2;                             // 33554432
static constexpr size_t RQ_OFF = AT_OFF + (size_t)BH * NCH * CC * CC;    // 37748736
static constexpr size_t RK_OFF = RQ_OFF + (size_t)BH * LQ;               // 37879808

__global__ __launch_bounds__(256) void dn_phase1(
    const float* __restrict__ q, const float* __restrict__ k,
    const float* __restrict__ v, const float* __restrict__ beta,
    float* __restrict__ ws)
{
    __shared__ float qc[CC][LDP];
    __shared__ float kc[CC][LDP];
    __shared__ float vc[CC][LDP];
    __shared__ float T[CC][TP];
    __shared__ float betas[CC], rqs[CC], rks[CC];

    const int tid = threadIdx.x;
    const int blk = blockIdx.x;
    const int bh  = blk >> 8;
    const int t   = blk & 255;
    const size_t gbase = ((size_t)bh * LQ + (size_t)t * CC) * DK;

    #pragma unroll
    for (int i = 0; i < 4; ++i) {
        int idx4 = i * 256 + tid;
        int row  = idx4 >> 5;
        int c4   = (idx4 & 31) << 2;
        *(float4*)&qc[row][c4] = *(const float4*)(q + gbase + (size_t)idx4 * 4);
        *(float4*)&kc[row][c4] = *(const float4*)(k + gbase + (size_t)idx4 * 4);
        *(float4*)&vc[row][c4] = *(const float4*)(v + gbase + (size_t)idx4 * 4);
    }
    if (tid < CC) betas[tid] = beta[(size_t)bh * LQ + (size_t)t * CC + tid];
    __syncthreads();

    {
        int row = tid >> 3, g = tid & 7;
        float sq = 0.f, sk = 0.f;
        #pragma unroll
        for (int i = 0; i < 4; ++i) {
            float4 a = *(float4*)&qc[row][g * 16 + i * 4];
            sq += a.x * a.x + a.y * a.y + a.z * a.z + a.w * a.w;
            float4 b = *(float4*)&kc[row][g * 16 + i * 4];
            sk += b.x * b.x + b.y * b.y + b.z * b.z + b.w * b.w;
        }
        sq += __shfl_xor(sq, 1); sq += __shfl_xor(sq, 2); sq += __shfl_xor(sq, 4);
        sk += __shfl_xor(sk, 1); sk += __shfl_xor(sk, 2); sk += __shfl_xor(sk, 4);
        if (g == 0) {
            rqs[row] = 1.f / sqrtf(sq + 1e-6f);
            rks[row] = 1.f / sqrtf(sk + 1e-6f);
        }
    }
    __syncthreads();

    if (tid < CC) {
        ws[RQ_OFF + (size_t)bh * LQ + (size_t)t * CC + tid] = rqs[tid];
        ws[RK_OFF + (size_t)bh * LQ + (size_t)t * CC + tid] = rks[tid];
    }

    #pragma unroll
    for (int i = 0; i < 4; ++i) {
        int idx4 = i * 256 + tid;
        int row  = idx4 >> 5;
        int c4   = (idx4 & 31) << 2;
        float rq_ = rqs[row], rk_ = rks[row];
        float4 a = *(float4*)&qc[row][c4];
        a.x *= rq_; a.y *= rq_; a.z *= rq_; a.w *= rq_;
        *(float4*)&qc[row][c4] = a;
        float4 b = *(float4*)&kc[row][c4];
        b.x *= rk_; b.y *= rk_; b.z *= rk_; b.w *= rk_;
        *(float4*)&kc[row][c4] = b;
    }
    __syncthreads();

    {
        int i  = tid >> 3;
        int j0 = (tid & 7) << 2;
        float aA[4] = {0.f, 0.f, 0.f, 0.f};
        float aQ[4] = {0.f, 0.f, 0.f, 0.f};
        for (int r4 = 0; r4 < 32; ++r4) {
            float4 ki = *(float4*)&kc[i][r4 << 2];
            float4 qi = *(float4*)&qc[i][r4 << 2];
            #pragma unroll
            for (int jj = 0; jj < 4; ++jj) {
                float4 kj = *(float4*)&kc[j0 + jj][r4 << 2];
                aA[jj] += ki.x * kj.x + ki.y * kj.y + ki.z * kj.z + ki.w * kj.w;
                aQ[jj] += qi.x * kj.x + qi.y * kj.y + qi.z * kj.z + qi.w * kj.w;
            }
        }
        float bi = betas[i];
        float at4[4];
        #pragma unroll
        for (int jj = 0; jj < 4; ++jj) {
            int j = j0 + jj;
            T[i][j] = (j < i) ? (-bi * aA[jj]) : 0.f;
            at4[jj] = (j <= i) ? aQ[jj] : 0.f;
        }
        *(float4*)(ws + AT_OFF + ((size_t)(bh * NCH + t) * CC + i) * CC + j0) =
            make_float4(at4[0], at4[1], at4[2], at4[3]);
    }
    __syncthreads();

    for (int i = 1; i < CC; ++i) {
        float upd = 0.f;
        if (tid < i) {
            float s = T[i][tid];
            for (int j = 0; j < CC; ++j) s += T[i][j] * T[j][tid];
            upd = s;
        }
        __syncthreads();
        if (tid < i) T[i][tid] = upd;
        __syncthreads();
    }

    {
        int i  = tid >> 3;
        int j0 = (tid & 7) << 2;
        #pragma unroll
        for (int jj = 0; jj < 4; ++jj) T[i][j0 + jj] *= betas[j0 + jj];
    }
    __syncthreads();

    {
        int i  = tid >> 3;
        int d0 = (tid & 7) << 4;
        float bi = betas[i];
        float4 aU[4], aW[4];
        #pragma unroll
        for (int d4 = 0; d4 < 4; ++d4) {
            float4 vv = *(float4*)&vc[i][d0 + d4 * 4];
            float4 kk = *(float4*)&kc[i][d0 + d4 * 4];
            aU[d4] = make_float4(bi * vv.x, bi * vv.y, bi * vv.z, bi * vv.w);
            aW[d4] = make_float4(bi * kk.x, bi * kk.y, bi * kk.z, bi * kk.w);
        }
        for (int j = 0; j < i; ++j) {
            float tb = T[i][j];
            #pragma unroll
            for (int d4 = 0; d4 < 4; ++d4) {
                float4 vv = *(float4*)&vc[j][d0 + d4 * 4];
                float4 kk = *(float4*)&kc[j][d0 + d4 * 4];
                aU[d4].x += tb * vv.x; aU[d4].y += tb * vv.y;
                aU[d4].z += tb * vv.z; aU[d4].w += tb * vv.w;
                aW[d4].x += tb * kk.x; aW[d4].y += tb * kk.y;
                aW[d4].z += tb * kk.z; aW[d4].w += tb * kk.w;
            }
        }
        size_t ob = (size_t)(bh * NCH + t) * (CC * DK) + (size_t)i * DK + d0;
        #pragma unroll
        for (int d4 = 0; d4 < 4; ++d4) {
            *(float4*)(ws + U0_OFF + ob + d4 * 4) = aU[d4];
            *(float4*)(ws + W_OFF  + ob + d4 * 4) = aW[d4];
        }
    }
}

// ---------------------------------------------------------------------------
// Phase 2 v3
// ---------------------------------------------------------------------------
__global__ __launch_bounds__(256, 1) void dn_phase2(
    const float* __restrict__ q, const float* __restrict__ k,
    const float* __restrict__ ws, float* __restrict__ out)
{
    __shared__ float wqA[64][LDP], wqB[64][LDP];  // rows 0-31: w, rows 32-63: raw q
    __shared__ float kA[CC][LDP],  kB[CC][LDP];   // raw k
    __shared__ float aA_[CC][TP],  aB_[CC][TP];   // attn (pre-masked)
    __shared__ float St[8][LDP];                   // S^T slice: St[col][row]
    __shared__ float um_[CC][12];                  // u
    __shared__ float u2_[CC][12];                  // rk * u
    __shared__ float qd_[CC][12];                  // rq * (q @ S)

    const int bh   = blockIdx.x >> 4;
    const int g    = blockIdx.x & 15;
    const int c0   = g * 8;
    const int tid  = threadIdx.x;
    const int lane = tid & 63;
    const int wv   = tid >> 6;

    // B roles: tid = m4*16 + c2*8 + ks
    const int m4 = tid >> 4;          // 0..15: rows {m4, m4+16} of w and q
    const int c2 = (tid >> 3) & 1;    // col group {4c2..4c2+3}
    const int ks = tid & 7;           // K-slice (lane bits 0-2)
    // C roles: tid = a2*16 + cc_*2 + jsC
    const int a2  = tid >> 4;         // rows {a2, a2+16}
    const int cc_ = (tid >> 1) & 7;   // col
    const int jsC = tid & 1;          // J-slice (lane bit 0)
    // D roles: rows {rb, rb+16}, cols {4chD..}, J-slice jsD (lane bit 5)
    const int rlow = lane & 15;
    const int chD  = (lane >> 4) & 1;
    const int jsD  = lane >> 5;
    const int rb   = 32 * wv + rlow;

    float sreg0[4] = {0.f, 0.f, 0.f, 0.f};   // S[rb][4chD..],    valid on jsD==0
    float sreg1[4] = {0.f, 0.f, 0.f, 0.f};   // S[rb+16][4chD..], valid on jsD==0

    // staging registers
    float4 sw0, sw1, sw2, sw3, sq0, sq1, sq2, sq3, sk0, sk1, sk2_, sk3, sat;
    float4 su0a, su0b;
    float  srqa, srqb, srka, srkb;
    // current-step scalars (B reducing lanes)
    float4 cu0a, cu0b;
    float  crqa, crqb, crka, crkb;

    auto issue = [&](int t) {
        const size_t wb = W_OFF + (size_t)(bh * NCH + t) * 4096;
        const size_t gb = ((size_t)bh * LQ + (size_t)t * CC) * DK;
        const size_t ab = AT_OFF + (size_t)(bh * NCH + t) * 1024;
        sw0 = *(const float4*)(ws + wb + (size_t)(0 * 256 + tid) * 4);
        sw1 = *(const float4*)(ws + wb + (size_t)(1 * 256 + tid) * 4);
        sw2 = *(const float4*)(ws + wb + (size_t)(2 * 256 + tid) * 4);
        sw3 = *(const float4*)(ws + wb + (size_t)(3 * 256 + tid) * 4);
        sq0 = *(const float4*)(q + gb + (size_t)(0 * 256 + tid) * 4);
        sq1 = *(const float4*)(q + gb + (size_t)(1 * 256 + tid) * 4);
        sq2 = *(const float4*)(q + gb + (size_t)(2 * 256 + tid) * 4);
        sq3 = *(const float4*)(q + gb + (size_t)(3 * 256 + tid) * 4);
        sk0 = *(const float4*)(k + gb + (size_t)(0 * 256 + tid) * 4);
        sk1 = *(const float4*)(k + gb + (size_t)(1 * 256 + tid) * 4);
        sk2_ = *(const float4*)(k + gb + (size_t)(2 * 256 + tid) * 4);
        sk3 = *(const float4*)(k + gb + (size_t)(3 * 256 + tid) * 4);
        sat = *(const float4*)(ws + ab + (size_t)tid * 4);
        if (ks == 0) {
            const size_t ub = U0_OFF + (size_t)(bh * NCH + t) * 4096;
            su0a = *(const float4*)(ws + ub + (size_t)m4 * DK + c0 + 4 * c2);
            su0b = *(const float4*)(ws + ub + (size_t)(m4 + 16) * DK + c0 + 4 * c2);
            const size_t rbse = (size_t)bh * LQ + (size_t)t * CC;
            srqa = ws[RQ_OFF + rbse + m4];
            srqb = ws[RQ_OFF + rbse + m4 + 16];
            srka = ws[RK_OFF + rbse + m4];
            srkb = ws[RK_OFF + rbse + m4 + 16];
        }
    };

    auto commit = [&](float (*wqT)[LDP], float (*kT)[LDP], float (*aT)[TP]) {
        {
            int gi = 0 * 256 + tid; int r = gi >> 5, c4 = (gi & 31) << 2;
            *(float4*)&wqT[r][c4] = sw0; *(float4*)&wqT[32 + r][c4] = sq0;
            *(float4*)&kT[r][c4] = sk0;
        }
        {
            int gi = 1 * 256 + tid; int r = gi >> 5, c4 = (gi & 31) << 2;
            *(float4*)&wqT[r][c4] = sw1; *(float4*)&wqT[32 + r][c4] = sq1;
            *(float4*)&kT[r][c4] = sk1;
        }
        {
            int gi = 2 * 256 + tid; int r = gi >> 5, c4 = (gi & 31) << 2;
            *(float4*)&wqT[r][c4] = sw2; *(float4*)&wqT[32 + r][c4] = sq2;
            *(float4*)&kT[r][c4] = sk2_;
        }
        {
            int gi = 3 * 256 + tid; int r = gi >> 5, c4 = (gi & 31) << 2;
            *(float4*)&wqT[r][c4] = sw3; *(float4*)&wqT[32 + r][c4] = sq3;
            *(float4*)&kT[r][c4] = sk3;
        }
        { int r = tid >> 3, c4 = (tid & 7) << 2; *(float4*)&aT[r][c4] = sat; }
    };

    float (*wqC)[LDP] = wqA, (*wqN)[LDP] = wqB;
    float (*kC)[LDP] = kA,  (*kN)[LDP] = kB;
    float (*aC)[TP] = aA_,  (*aN)[TP] = aB_;

    // prologue
    for (int idx = tid; idx < 8 * LDP; idx += 256) ((float*)St)[idx] = 0.f;
    issue(0);
    commit(wqC, kC, aC);
    cu0a = su0a; cu0b = su0b;
    crqa = srqa; crqb = srqb; crka = srka; crkb = srkb;
    __syncthreads();

    for (int t = 0; t < NCH; ++t) {
        if (t + 1 < NCH) issue(t + 1);

        // ---- B: [w;q] @ S, 4x4 tile per thread, K/8 over lane bits 0-2 ----
        float accW0[4] = {0,0,0,0}, accW1[4] = {0,0,0,0};
        float accQ0[4] = {0,0,0,0}, accQ1[4] = {0,0,0,0};
        #pragma unroll
        for (int it = 0; it < 4; ++it) {
            const int kb = ks * 16 + it * 4;
            float4 aw0 = *(float4*)&wqC[m4][kb];
            float4 aw1 = *(float4*)&wqC[m4 + 16][kb];
            float4 aq0 = *(float4*)&wqC[32 + m4][kb];
            float4 aq1 = *(float4*)&wqC[48 + m4][kb];
            #pragma unroll
            for (int cc = 0; cc < 4; ++cc) {
                float4 sv = *(float4*)&St[4 * c2 + cc][kb];
                accW0[cc] += aw0.x * sv.x + aw0.y * sv.y + aw0.z * sv.z + aw0.w * sv.w;
                accW1[cc] += aw1.x * sv.x + aw1.y * sv.y + aw1.z * sv.z + aw1.w * sv.w;
                accQ0[cc] += aq0.x * sv.x + aq0.y * sv.y + aq0.z * sv.z + aq0.w * sv.w;
                accQ1[cc] += aq1.x * sv.x + aq1.y * sv.y + aq1.z * sv.z + aq1.w * sv.w;
            }
        }
        #pragma unroll
        for (int m = 1; m <= 4; m <<= 1) {
            #pragma unroll
            for (int cc = 0; cc < 4; ++cc) {
                accW0[cc] += __shfl_xor(accW0[cc], m);
                accW1[cc] += __shfl_xor(accW1[cc], m);
                accQ0[cc] += __shfl_xor(accQ0[cc], m);
                accQ1[cc] += __shfl_xor(accQ1[cc], m);
            }
        }
        if (ks == 0) {
            float ua[4], ub[4];
            ua[0] = cu0a.x - accW0[0]; ua[1] = cu0a.y - accW0[1];
            ua[2] = cu0a.z - accW0[2]; ua[3] = cu0a.w - accW0[3];
            ub[0] = cu0b.x - accW1[0]; ub[1] = cu0b.y - accW1[1];
            ub[2] = cu0b.z - accW1[2]; ub[3] = cu0b.w - accW1[3];
            *(float4*)&um_[m4][4 * c2]      = make_float4(ua[0], ua[1], ua[2], ua[3]);
            *(float4*)&um_[m4 + 16][4 * c2] = make_float4(ub[0], ub[1], ub[2], ub[3]);
            *(float4*)&u2_[m4][4 * c2] =
                make_float4(ua[0] * crka, ua[1] * crka, ua[2] * crka, ua[3] * crka);
            *(float4*)&u2_[m4 + 16][4 * c2] =
                make_float4(ub[0] * crkb, ub[1] * crkb, ub[2] * crkb, ub[3] * crkb);
            *(float4*)&qd_[m4][4 * c2] =
                make_float4(accQ0[0] * crqa, accQ0[1] * crqa, accQ0[2] * crqa, accQ0[3] * crqa);
            *(float4*)&qd_[m4 + 16][4 * c2] =
                make_float4(accQ1[0] * crqb, accQ1[1] * crqb, accQ1[2] * crqb, accQ1[3] * crqb);
        }
        __syncthreads();   // barrier 1: um/u2/qd ready

        // ---- C: o = qd + attn @ um, 2 rows/thread, J/2 over lane bit 0 ----
        float oa = 0.f, ob = 0.f;
        #pragma unroll
        for (int jt = 0; jt < 4; ++jt) {
            const int j = jsC * 16 + jt * 4;
            float4 t0 = *(float4*)&aC[a2][j];
            float4 t1 = *(float4*)&aC[a2 + 16][j];
            float v0 = um_[j][cc_],     v1 = um_[j + 1][cc_];
            float v2 = um_[j + 2][cc_], v3 = um_[j + 3][cc_];
            oa += t0.x * v0 + t0.y * v1 + t0.z * v2 + t0.w * v3;
            ob += t1.x * v0 + t1.y * v1 + t1.z * v2 + t1.w * v3;
        }
        oa += __shfl_xor(oa, 1);
        ob += __shfl_xor(ob, 1);
        if (jsC == 0) {
            const size_t orow = (size_t)bh * LQ + (size_t)t * CC;
            out[(orow + a2) * DK + c0 + cc_]      = oa + qd_[a2][cc_];
            out[(orow + a2 + 16) * DK + c0 + cc_] = ob + qd_[a2 + 16][cc_];
        }

        // ---- D: S += k^T @ u2, 2x4 tile/thread, J/2 over lane bit 5 ----
        float p0[4] = {0,0,0,0}, p1[4] = {0,0,0,0};
        #pragma unroll
        for (int jt = 0; jt < 4; ++jt) {
            const int j = jsD * 16 + jt * 4;
            #pragma unroll
            for (int jj = 0; jj < 4; ++jj) {
                float  kv0 = kC[j + jj][rb];
                float  kv1 = kC[j + jj][rb + 16];
                float4 uv  = *(float4*)&u2_[j + jj][4 * chD];
                p0[0] += kv0 * uv.x; p0[1] += kv0 * uv.y;
                p0[2] += kv0 * uv.z; p0[3] += kv0 * uv.w;
                p1[0] += kv1 * uv.x; p1[1] += kv1 * uv.y;
                p1[2] += kv1 * uv.z; p1[3] += kv1 * uv.w;
            }
        }
        #pragma unroll
        for (int i = 0; i < 4; ++i) {
            p0[i] += __shfl_xor(p0[i], 32);
            p1[i] += __shfl_xor(p1[i], 32);
        }
        if (jsD == 0) {
            #pragma unroll
            for (int i = 0; i < 4; ++i) { sreg0[i] += p0[i]; sreg1[i] += p1[i]; }
            #pragma unroll
            for (int cc = 0; cc < 4; ++cc) {
                St[4 * chD + cc][rb]      = sreg0[cc];
                St[4 * chD + cc][rb + 16] = sreg1[cc];
            }
        }

        // ---- rotate double buffers ----
        if (t + 1 < NCH) {
            commit(wqN, kN, aN);
            cu0a = su0a; cu0b = su0b;
            crqa = srqa; crqb = srqb; crka = srka; crkb = srkb;
            float (*tw)[LDP] = wqC; wqC = wqN; wqN = tw;
            float (*tk)[LDP] = kC;  kC  = kN;  kN  = tk;
            float (*ta)[TP]  = aC;  aC  = aN;  aN  = ta;
        }
        __syncthreads();   // barrier 2: St + next buffers ready
    }

    // final state S -> out
    if (jsD == 0) {
        const size_t sbase = (size_t)BH * LQ * DK + (size_t)bh * DK * DK;
        *(float4*)(out + sbase + (size_t)rb * DK + c0 + 4 * chD) =
            make_float4(sreg0[0], sreg0[1], sreg0[2], sreg0[3]);
        *(float4*)(out + sbase + (size_t)(rb + 16) * DK + c0 + 4 * chD) =
            make_float4(sreg1[0], sreg1[1], sreg1[2], sreg1[3]);
    }
}

extern "C" void kernel_launch(void* const* d_in, const int* in_sizes, int n_in,
                              void* d_out, int out_size, void* d_ws, size_t ws_size,
                              hipStream_t stream) {
    (void)in_sizes; (void)n_in; (void)out_size; (void)ws_size;
    const float* q    = (const float*)d_in[0];
    const float* k    = (const float*)d_in[1];
    const float* v    = (const float*)d_in[2];
    const float* beta = (const float*)d_in[3];
    float* ws  = (float*)d_ws;
    float* out = (float*)d_out;

    dn_phase1<<<BH * NCH, 256, 0, stream>>>(q, k, v, beta, ws);
    dn_phase2<<<BH * 16, 256, 0, stream>>>(q, k, ws, out);
}